// Round 1
// baseline (247.525 us; speedup 1.0000x reference)
//
#include <hip/hip_runtime.h>

// Muskingum-Cunge routing, MI355X.
// Key insight: output = Q[level 15, reach 2047] only -> compute the single
// outlet chain. 16-lane systolic pipeline (lane = level) walks the DAG's
// anti-diagonal wavefront: 2920+16 macro steps, DPP row_shr:1 hands Q_new
// from level l to l+1. Pure latency-bound dependent chain.

#define T_STEPS 730
#define N_REACH 32768
#define P_REACH 2048
#define JTOT    (T_STEPS * 4)   // 2920 substeps total
#define KTOT    2936            // (JTOT + 15) padded to multiple of 4
#define HDT     10800.0f        // 0.5 * (86400/4)
#define QMIN    1e-3f
#define C23     0.41774484f     // 0.27^(2/3)
#define RCMAX   600.0f          // 1 / ((5/3) * 1e-3)  (velocity floor image)
#define LOG2E   1.4426950408889634f

__device__ __forceinline__ float dpp_up1(float x) {
    // lane l <- lane l-1 within each row of 16; bound_ctrl=1 => lane 0 gets 0
    int r = __builtin_amdgcn_mov_dpp(__float_as_int(x), 0x111, 0xF, 0xF, true);
    return __int_as_float(r);
}

__global__ __launch_bounds__(1024, 1)
void mc_route(const float* __restrict__ inflow,
              const float* __restrict__ log_n,
              const float* __restrict__ dxs,
              const float* __restrict__ slopes,
              float* __restrict__ out)
{
    // lat table: 4 leading zero t-slots (pipeline fill -> exact 0 fixed point),
    // then 730 x 16 staged lateral inflows for the outlet chain (p = 2047).
    __shared__ float lat_s[(T_STEPS + 4) * 16];

    const int tid = threadIdx.x;
    if (tid < 64) lat_s[tid] = 0.0f;
    #pragma unroll 4
    for (int i = tid; i < T_STEPS * 16; i += 1024) {
        // i = t*16 + l  ->  inflow[t*32768 + l*2048 + 2047]
        lat_s[64 + i] = inflow[(i >> 4) * N_REACH + (i & 15) * P_REACH + (P_REACH - 1)];
    }
    __syncthreads();
    if (tid >= 64) return;   // only wave 0 runs the pipeline

    const int lane = tid;
    const int lvl  = lane < 15 ? lane : 15;       // lanes 16..63 ride along (benign)
    const int g    = lvl * P_REACH + (P_REACH - 1);

    const float nman  = __builtin_amdgcn_exp2f(log_n[g] * LOG2E);
    const float dx    = dxs[g];
    const float S     = slopes[g];
    // vel = C23 * Qref^0.2 * sqrt(S)/n ; c = (5/3)*max(vel,1e-3)
    // rc  = 1/c = min(invA2 * Qref^-0.2, RCMAX)
    const float invA2 = nman / (1.6666666667f * C23 * __builtin_amdgcn_sqrtf(S));
    // X = clip(0.5 - 0.5*sqrt(Qref)/(7.2*S*dx*c), 0, 0.5) = clip(0.5 - Bh*sqrt(Qref)*rc)
    const float Bh    = 0.5f / (7.2f * S * dx);

    float Qold = 0.0f, Iold = 0.0f, Qprev = 0.0f;

    auto lataddr = [&](int kk) {
        int t = (kk - lvl) >> 2;                  // arithmetic shift: floor div
        t = t > (T_STEPS - 1) ? (T_STEPS - 1) : t; // top clamp (drain garbage, unused)
        return (t + 4) * 16 + lvl;                // t in [-4,..] -> zero slots
    };

    // 4-deep register-rotated LDS prefetch: issue->use distance ~4 macro steps
    float b0 = lat_s[lataddr(0)];
    float b1 = lat_s[lataddr(1)];
    float b2 = lat_s[lataddr(2)];
    float b3 = lat_s[lataddr(3)];

#define STEP(KK, BUF, DO_STORE)                                            \
    {                                                                      \
        const float lat = BUF;                                             \
        BUF = lat_s[lataddr((KK) + 4)];  /* prefetch, off critical path */ \
        const float up   = dpp_up1(Qprev);                                 \
        const float Inew = up + lat;                                       \
        const float sI   = Inew + Iold - Qold;   /* early, off path */     \
        const float dI   = Iold - Inew;                                    \
        const float Qref = fmaxf(fmaf(0.5f, Inew, 0.5f * Qold), QMIN);     \
        const float lg   = __builtin_amdgcn_logf(Qref);                    \
        const float em   = __builtin_amdgcn_exp2f(-0.2f * lg);             \
        const float rc   = fminf(invA2 * em, RCMAX);                       \
        const float sq   = __builtin_amdgcn_sqrtf(Qref); /* parallel */    \
        const float K    = dx * rc;                                        \
        float X = fmaf(-(Bh * sq), rc, 0.5f);                              \
        X = fmaxf(0.0f, fminf(0.5f, X));                                   \
        const float KX   = K * X;                                          \
        const float Km   = K - KX;               /* K*(1-X) */             \
        const float rd   = __builtin_amdgcn_rcpf(Km + HDT);                \
        /* C0*Inew+C1*Iold+C2*Qold = [hdt*sI + KX*dI + Km*Qold] / denom */ \
        const float num  = fmaf(KX, dI, fmaf(Km, Qold, HDT * sI));         \
        const float Qnew = fmaxf(num * rd, 0.0f);                          \
        if (DO_STORE) {                                                    \
            int j = (KK) - 15;   /* lane 15's substep; j&3==3 at this phase */ \
            if (lane == 15 && (unsigned)j < (unsigned)JTOT)                \
                out[j >> 2] = Qnew;                                        \
        }                                                                  \
        Qold = Qnew; Iold = Inew; Qprev = Qnew;  /* unconditional: exact */ \
    }

    for (int k = 0; k < KTOT; k += 4) {
        STEP(k + 0, b0, false)
        STEP(k + 1, b1, false)
        STEP(k + 2, b2, true)    // k ≡ 2 (mod 4): lane15 j ≡ 3 (mod 4) -> timestep end
        STEP(k + 3, b3, false)
    }
#undef STEP
}

extern "C" void kernel_launch(void* const* d_in, const int* in_sizes, int n_in,
                              void* d_out, int out_size, void* d_ws, size_t ws_size,
                              hipStream_t stream) {
    const float* inflow = (const float*)d_in[0];
    const float* log_n  = (const float*)d_in[1];
    const float* dxs    = (const float*)d_in[2];
    const float* slopes = (const float*)d_in[3];
    float* out = (float*)d_out;
    mc_route<<<1, 1024, 0, stream>>>(inflow, log_n, dxs, slopes, out);
}

// Round 2
// 176.563 us; speedup vs baseline: 1.4019x; 1.4019x over previous
//
#include <hip/hip_runtime.h>

// Muskingum-Cunge routing, MI355X — single outlet chain (out = Q[15, 2047]).
// 16-lane systolic pipeline, lane = level, DPP row_shr:1 handoff.
// Exact-algebra chain compression:
//   Kh   = K/2        = exp2(-0.2*log2(Qref) + lKh)      (lKh = log2(0.5*dx*invA2))
//   Ku   = K*u        = exp2( 0.1*log2(Qref) + lKu)      (lKu = log2(0.5*invA2^2/(7.2*S)))
//   Kmin = K*min(u,.5) = min(Ku, Kh)   [X-clamp, exact since K>0]
//   KX = Kh-Kmin, Km = Kh+Kmin, denom = Kh+HDT+Kmin
//   num = Kh*P1 + Kmin*P2 + HDT*sI,  P1 = Iold-Inew+Qold, P2 = Inew-(Iold-Qold)
//   Qnew = max(num,0) * rcp(denom)
// Critical chain: dpp-add, fmaf, max, log, fmaf, exp2, min, add, rcp, mul (10 slots, 3 trans).

#define T_STEPS 730
#define NROWS   (T_STEPS + 10)   // 4 leading zero rows + 730 data + 6 zero pad
#define HDT     10800.0f         // 0.5 * (86400/4)
#define QMIN    1e-3f

__global__ __launch_bounds__(1024, 1)
void mc_route(const float* __restrict__ inflow,
              const float* __restrict__ log_n,
              const float* __restrict__ dxs,
              const float* __restrict__ slopes,
              float* __restrict__ out)
{
    __shared__ float lat_s[NROWS * 16];

    const int tid = threadIdx.x;
    for (int i = tid; i < NROWS * 16; i += 1024) {
        int t = (i >> 4) - 4;
        float v = 0.0f;
        if ((unsigned)t < (unsigned)T_STEPS)
            v = inflow[t * 32768 + (i & 15) * 2048 + 2047];
        lat_s[i] = v;
    }
    __syncthreads();
    if (tid >= 64) return;       // wave 0 runs the pipeline

    const int lane = tid;
    const int lvl  = lane < 15 ? lane : 15;   // lanes 16..63 ride along (benign)
    const int g    = lvl * 2048 + 2047;

    const float nman  = expf(log_n[g]);
    const float dx    = dxs[g];
    const float S     = slopes[g];
    // rc = 1/c = invA2 * Qref^-0.2 ; invA2 = n / ((5/3)*0.27^(2/3)*sqrt(S))
    const float invA2 = 1.4362849f * nman / __builtin_amdgcn_sqrtf(S);
    const float lKh   = log2f(0.5f * dx * invA2);
    const float lKu   = log2f(0.5f * invA2 * invA2 / (7.2f * S));

    // 4 rotating LDS pointers: buffer j loaded at steps KK===j (mod 4) for KK+4.
    // Pointer row for block base: 5 + floor((j-lvl)/4); in-block imm offsets q*16 floats.
    const float* p0 = lat_s + (5 + ((0 - lvl) >> 2)) * 16 + lvl;
    const float* p1 = lat_s + (5 + ((1 - lvl) >> 2)) * 16 + lvl;
    const float* p2 = lat_s + (5 + ((2 - lvl) >> 2)) * 16 + lvl;
    const float* p3 = lat_s + (5 + ((3 - lvl) >> 2)) * 16 + lvl;

    // Prefill: b_j = lat(t = floor((j-lvl)/4)), rows 0..4 (rows<4 are zeros).
    float b0 = lat_s[(4 + ((0 - lvl) >> 2)) * 16 + lvl];
    float b1 = lat_s[(4 + ((1 - lvl) >> 2)) * 16 + lvl];
    float b2 = lat_s[(4 + ((2 - lvl) >> 2)) * 16 + lvl];
    float b3 = lat_s[(4 + ((3 - lvl) >> 2)) * 16 + lvl];

    // State: Qprev (=Qold), hQold = 0.5*Qold, D = Iold-Qold, hD = HDT*D, SIQ = Iold+Qold.
    float Qprev = 0.0f, hQold = 0.0f, D = 0.0f, hD = 0.0f, SIQ = 0.0f;

#define STEP(BUF, LD, ST) do {                                                        \
    const float lat  = BUF;                                                           \
    BUF = (LD);                           /* prefetch for KK+4, off chain */          \
    const int   upi  = __builtin_amdgcn_update_dpp(0, __float_as_int(Qprev),          \
                                                   0x111, 0xF, 0xF, true);            \
    const float Inew = __int_as_float(upi) + lat;                                     \
    const float Qref = fmaxf(fmaf(0.5f, Inew, hQold), QMIN);                          \
    const float lg   = __builtin_amdgcn_logf(Qref);                                   \
    const float Ku   = __builtin_amdgcn_exp2f(fmaf( 0.1f, lg, lKu));                  \
    const float Kh   = __builtin_amdgcn_exp2f(fmaf(-0.2f, lg, lKh));                  \
    const float Kmin = fminf(Ku, Kh);                                                 \
    const float rd   = __builtin_amdgcn_rcpf((Kh + HDT) + Kmin);                      \
    const float P1   = SIQ - Inew;                                                    \
    const float P2   = Inew - D;                                                      \
    const float hsI  = fmaf(HDT, Inew, hD);                                           \
    const float num  = fmaf(Kmin, P2, fmaf(Kh, P1, hsI));                             \
    const float Qnew = fmaxf(num, 0.0f) * rd;                                         \
    ST;                                                                               \
    D = Inew - Qnew; hD = HDT * D; SIQ = Inew + Qnew;                                 \
    hQold = 0.5f * Qnew; Qprev = Qnew;                                                \
} while (0);

    // ---- Prologue: KK = 0..15, no valid stores (lane15 j = KK-15 < 3) ----
    STEP(b0, p0[0],  {}) STEP(b1, p1[0],  {}) STEP(b2, p2[0],  {}) STEP(b3, p3[0],  {})
    STEP(b0, p0[16], {}) STEP(b1, p1[16], {}) STEP(b2, p2[16], {}) STEP(b3, p3[16], {})
    STEP(b0, p0[32], {}) STEP(b1, p1[32], {}) STEP(b2, p2[32], {}) STEP(b3, p3[32], {})
    STEP(b0, p0[48], {}) STEP(b1, p1[48], {}) STEP(b2, p2[48], {}) STEP(b3, p3[48], {})
    p0 += 64; p1 += 64; p2 += 64; p3 += 64;

    // ---- Main: 182 blocks of 16 steps; KK = 16..2927; stores idx 0..727 ----
    float* outp = out;
    #pragma unroll 1
    for (int blk = 0; blk < 182; ++blk) {
        float4 st;
        STEP(b0, p0[0],  {}) STEP(b1, p1[0],  {}) STEP(b2, p2[0],  st.x = Qnew) STEP(b3, p3[0],  {})
        STEP(b0, p0[16], {}) STEP(b1, p1[16], {}) STEP(b2, p2[16], st.y = Qnew) STEP(b3, p3[16], {})
        STEP(b0, p0[32], {}) STEP(b1, p1[32], {}) STEP(b2, p2[32], st.z = Qnew) STEP(b3, p3[32], {})
        STEP(b0, p0[48], {}) STEP(b1, p1[48], {}) STEP(b2, p2[48], st.w = Qnew) STEP(b3, p3[48], {})
        if (lane == 15) *reinterpret_cast<float4*>(outp) = st;
        outp += 4;
        p0 += 64; p1 += 64; p2 += 64; p3 += 64;
    }

    // ---- Epilogue: KK = 2928..2935; stores idx 728 (KK=2930), 729 (KK=2934) ----
    {
        float2 st2;
        STEP(b0, p0[0],  {}) STEP(b1, p1[0],  {}) STEP(b2, p2[0],  st2.x = Qnew) STEP(b3, p3[0],  {})
        STEP(b0, p0[16], {}) STEP(b1, p1[16], {}) STEP(b2, p2[16], st2.y = Qnew) STEP(b3, p3[16], {})
        if (lane == 15) *reinterpret_cast<float2*>(out + 728) = st2;
    }
#undef STEP
}

extern "C" void kernel_launch(void* const* d_in, const int* in_sizes, int n_in,
                              void* d_out, int out_size, void* d_ws, size_t ws_size,
                              hipStream_t stream) {
    const float* inflow = (const float*)d_in[0];
    const float* log_n  = (const float*)d_in[1];
    const float* dxs    = (const float*)d_in[2];
    const float* slopes = (const float*)d_in[3];
    float* out = (float*)d_out;
    mc_route<<<1, 1024, 0, stream>>>(inflow, log_n, dxs, slopes, out);
}